// Round 2
// baseline (3274.665 us; speedup 1.0000x reference)
//
#include <hip/hip_runtime.h>
#include <stdint.h>

// ShuffleWindowAttention on MI355X (gfx950), fp32 I/O.
// K1: split qkv_w/proj_w fp32 -> (bf16 hi, bf16 lo) pairs in d_ws (4 MB).
// K2: one WG per window: shuffle-gather X -> LDS hi/lo, per head QKV GEMM
//     (MFMA bf16 3-term split), S=q.k^T MFMA + in-register softmax, PV MFMA,
//     write attn-out packed (hi<<16|lo) u32 into d_out (un-shuffled position).
// K3: in-place proj GEMM over d_out rows (shuffle cancels): each WG owns 64
//     full rows; stages them to LDS before barrier, writes fp32 after compute.

typedef short bf16x8 __attribute__((ext_vector_type(8)));
typedef float f32x4 __attribute__((ext_vector_type(4)));
typedef unsigned short u16;
typedef unsigned int u32;

#define MFMA16(a, b, c) __builtin_amdgcn_mfma_f32_16x16x32_bf16((a), (b), (c), 0, 0, 0)

__device__ __forceinline__ u16 f2bf(float f) {
  union { float f; u32 u; } v; v.f = f;
  u32 x = v.u;
  return (u16)((x + 0x7FFFu + ((x >> 16) & 1u)) >> 16);  // RNE; inputs finite
}
__device__ __forceinline__ float bf2f(u16 b) {
  union { u32 u; float f; } v; v.u = ((u32)b) << 16; return v.f;
}
__device__ __forceinline__ void splitf(float f, u16& hi, u16& lo) {
  hi = f2bf(f);
  lo = f2bf(f - bf2f(hi));
}

// ---------------- ws layout (u16 elements) ----------------
// Whi[1536*512], Wlo[1536*512], Phi[512*512], Plo[512*512]  -> 4 MB total
#define WS_WHI 0
#define WS_WLO 786432
#define WS_PHI 1572864
#define WS_PLO 1835008

// ============ K1: weight split ============
__global__ void prep_weights(const float* __restrict__ qkv_w,
                             const float* __restrict__ proj_w,
                             u16* __restrict__ ws) {
  int i = (blockIdx.x * 256 + threadIdx.x) * 4;
  if (i < 786432) {
    float4 v = *(const float4*)(qkv_w + i);
    u16 h0, l0, h1, l1, h2, l2, h3, l3;
    splitf(v.x, h0, l0); splitf(v.y, h1, l1); splitf(v.z, h2, l2); splitf(v.w, h3, l3);
    ushort4 hs = make_ushort4(h0, h1, h2, h3);
    ushort4 ls = make_ushort4(l0, l1, l2, l3);
    *(ushort4*)(ws + WS_WHI + i) = hs;
    *(ushort4*)(ws + WS_WLO + i) = ls;
  } else {
    int j = i - 786432;  // < 262144
    float4 v = *(const float4*)(proj_w + j);
    u16 h0, l0, h1, l1, h2, l2, h3, l3;
    splitf(v.x, h0, l0); splitf(v.y, h1, l1); splitf(v.z, h2, l2); splitf(v.w, h3, l3);
    ushort4 hs = make_ushort4(h0, h1, h2, h3);
    ushort4 ls = make_ushort4(l0, l1, l2, l3);
    *(ushort4*)(ws + WS_PHI + j) = hs;
    *(ushort4*)(ws + WS_PLO + j) = ls;
  }
}

// ============ K2: per-window QKV + attention ============
// LDS layout (bytes). X tiles are [49][512] bf16 pitch 1024B, XOR-swizzled:
// byte ^= ((row&7)<<4). q/k: [49][64] pitch 128B; v stored TRANSPOSED
// [d=64][c=64] pitch 128B (pad cols c>=49 zeroed once); P: [64][64] pitch 128B.
// MFMA fragment reads of rows beyond 49 spill into following buffers --
// garbage there only feeds discarded output rows (element-independent MFMA).
#define L_XHI 0
#define L_XLO 50176
#define L_QHI 100352
#define L_QLO 106624
#define L_KHI 112896
#define L_KLO 119168
#define L_VHI 125440
#define L_VLO 133632
#define L_PHI 141824
#define L_PLO 150016
#define K2_SMEM 158208

#define SWZ(byte, row) ((byte) ^ (((row) & 7) << 4))

__global__ void __launch_bounds__(256, 1)
attn_win(const float* __restrict__ x, const float* __restrict__ qkv_b,
         const u16* __restrict__ ws, u32* __restrict__ outp) {
  extern __shared__ char smem[];
  const int tid = threadIdx.x;
  const int win = blockIdx.x;
  const int b = win >> 9, wi = win & 511;
  const u16* Whi = ws + WS_WHI;
  const u16* Wlo = ws + WS_WLO;
  const float* xw = x + ((size_t)b * 25088 + wi) * 512;

  // ---- Phase A: stage X (shuffle-gather) as hi/lo bf16; zero v_T ----
  for (int i = tid; i < 49 * 128; i += 256) {
    int s = i >> 7, c4 = i & 127;
    float4 v = *((const float4*)(xw + (size_t)s * 262144) + c4);
    u16 h0, l0, h1, l1, h2, l2, h3, l3;
    splitf(v.x, h0, l0); splitf(v.y, h1, l1); splitf(v.z, h2, l2); splitf(v.w, h3, l3);
    int byte = SWZ((s << 10) + (c4 << 3), s);
    *(ushort4*)(smem + L_XHI + byte) = make_ushort4(h0, h1, h2, h3);
    *(ushort4*)(smem + L_XLO + byte) = make_ushort4(l0, l1, l2, l3);
  }
  for (int i = tid; i < 4096; i += 256) ((u32*)(smem + L_VHI))[i] = 0u;  // vhi+vlo
  __syncthreads();

  const int lane = tid & 63, wv = tid >> 6;
  const int l15 = lane & 15, l4 = lane >> 4;
  const int ncol = wv * 16 + l15;  // this wave's column within a 64-wide head slice

  for (int h = 0; h < 8; ++h) {
    // ---- Phase B: QKV GEMM for head h (wave wv -> 16-col slice of q,k,v) ----
    float bq = qkv_b[h * 64 + ncol];
    float bk = qkv_b[512 + h * 64 + ncol];
    float bv = qkv_b[1024 + h * 64 + ncol];
    const size_t nq = (size_t)(h * 64 + ncol) * 512;
    const size_t nk = (size_t)(512 + h * 64 + ncol) * 512;
    const size_t nv = (size_t)(1024 + h * 64 + ncol) * 512;

    f32x4 acc[4][3] = {};
#pragma unroll 4
    for (int ks = 0; ks < 16; ++ks) {
      int koff = ks * 32 + l4 * 8;
      bf16x8 ah[4], al[4];
#pragma unroll
      for (int mt = 0; mt < 4; ++mt) {
        int row = mt * 16 + l15;
        int byte = SWZ((row << 10) + (koff << 1), row);
        ah[mt] = *(const bf16x8*)(smem + L_XHI + byte);
        al[mt] = *(const bf16x8*)(smem + L_XLO + byte);
      }
      bf16x8 bh0 = *(const bf16x8*)(Whi + nq + koff);
      bf16x8 bl0 = *(const bf16x8*)(Wlo + nq + koff);
      bf16x8 bh1 = *(const bf16x8*)(Whi + nk + koff);
      bf16x8 bl1 = *(const bf16x8*)(Wlo + nk + koff);
      bf16x8 bh2 = *(const bf16x8*)(Whi + nv + koff);
      bf16x8 bl2 = *(const bf16x8*)(Wlo + nv + koff);
#pragma unroll
      for (int mt = 0; mt < 4; ++mt) {
        acc[mt][0] = MFMA16(ah[mt], bh0, acc[mt][0]);
        acc[mt][0] = MFMA16(ah[mt], bl0, acc[mt][0]);
        acc[mt][0] = MFMA16(al[mt], bh0, acc[mt][0]);
        acc[mt][1] = MFMA16(ah[mt], bh1, acc[mt][1]);
        acc[mt][1] = MFMA16(ah[mt], bl1, acc[mt][1]);
        acc[mt][1] = MFMA16(al[mt], bh1, acc[mt][1]);
        acc[mt][2] = MFMA16(ah[mt], bh2, acc[mt][2]);
        acc[mt][2] = MFMA16(ah[mt], bl2, acc[mt][2]);
        acc[mt][2] = MFMA16(al[mt], bh2, acc[mt][2]);
      }
    }
    // epilogue: bias, scale q, split hi/lo, write q/k (row-major) and v (transposed)
#pragma unroll
    for (int mt = 0; mt < 4; ++mt) {
#pragma unroll
      for (int r = 0; r < 4; ++r) {
        int row = mt * 16 + l4 * 4 + r;
        if (row < 49) {
          float qv = (acc[mt][0][r] + bq) * 0.125f;
          float kv = acc[mt][1][r] + bk;
          float vv = acc[mt][2][r] + bv;
          u16 hi, lo;
          int qb = SWZ((row << 7) + (ncol << 1), row);
          splitf(qv, hi, lo);
          *(u16*)(smem + L_QHI + qb) = hi; *(u16*)(smem + L_QLO + qb) = lo;
          splitf(kv, hi, lo);
          *(u16*)(smem + L_KHI + qb) = hi; *(u16*)(smem + L_KLO + qb) = lo;
          int vb = SWZ((ncol << 7) + (row << 1), ncol);  // v_T[d=ncol][c=row]
          splitf(vv, hi, lo);
          *(u16*)(smem + L_VHI + vb) = hi; *(u16*)(smem + L_VLO + vb) = lo;
        }
      }
    }
    __syncthreads();

    // ---- Phase C: S = q.k^T (wave wv owns rows [16wv,16wv+16)) + softmax ----
    f32x4 sacc[4] = {};
#pragma unroll
    for (int ks = 0; ks < 2; ++ks) {
      int koff = ks * 32 + l4 * 8;
      int qrow = wv * 16 + l15;
      int qb = SWZ((qrow << 7) + (koff << 1), qrow);
      bf16x8 qh = *(const bf16x8*)(smem + L_QHI + qb);
      bf16x8 ql = *(const bf16x8*)(smem + L_QLO + qb);
#pragma unroll
      for (int nt = 0; nt < 4; ++nt) {
        int krow = nt * 16 + l15;
        int kb = SWZ((krow << 7) + (koff << 1), krow);
        bf16x8 kh = *(const bf16x8*)(smem + L_KHI + kb);
        bf16x8 kl = *(const bf16x8*)(smem + L_KLO + kb);
        sacc[nt] = MFMA16(qh, kh, sacc[nt]);
        sacc[nt] = MFMA16(qh, kl, sacc[nt]);
        sacc[nt] = MFMA16(ql, kh, sacc[nt]);
      }
    }
    // in-register softmax: row = 16wv + l4*4 + r; cols spread over 16 lanes x 4 tiles
#pragma unroll
    for (int r = 0; r < 4; ++r) {
      int prow = wv * 16 + l4 * 4 + r;
      float mx = -1e30f;
#pragma unroll
      for (int nt = 0; nt < 4; ++nt)
        if (nt * 16 + l15 < 49) mx = fmaxf(mx, sacc[nt][r]);
      mx = fmaxf(mx, __shfl_xor(mx, 1));
      mx = fmaxf(mx, __shfl_xor(mx, 2));
      mx = fmaxf(mx, __shfl_xor(mx, 4));
      mx = fmaxf(mx, __shfl_xor(mx, 8));
      float p[4]; float sum = 0.f;
#pragma unroll
      for (int nt = 0; nt < 4; ++nt) {
        p[nt] = (nt * 16 + l15 < 49) ? __expf(sacc[nt][r] - mx) : 0.f;
        sum += p[nt];
      }
      sum += __shfl_xor(sum, 1);
      sum += __shfl_xor(sum, 2);
      sum += __shfl_xor(sum, 4);
      sum += __shfl_xor(sum, 8);
      float inv = 1.f / sum;
#pragma unroll
      for (int nt = 0; nt < 4; ++nt) {
        float pv = p[nt] * inv;  // pad cols (>=49) are exactly 0
        u16 hi, lo; splitf(pv, hi, lo);
        int pb = SWZ((prow << 7) + ((nt * 16 + l15) << 1), prow);
        *(u16*)(smem + L_PHI + pb) = hi;
        *(u16*)(smem + L_PLO + pb) = lo;
      }
    }
    __syncthreads();

    // ---- Phase D: O = P.V (K-dim padded with P=0 cols, v_T zeroed pads) ----
    f32x4 oacc[4] = {};
#pragma unroll
    for (int ks = 0; ks < 2; ++ks) {
      int koff = ks * 32 + l4 * 8;
      int prow = wv * 16 + l15;
      int pb = SWZ((prow << 7) + (koff << 1), prow);
      bf16x8 ph = *(const bf16x8*)(smem + L_PHI + pb);
      bf16x8 pl = *(const bf16x8*)(smem + L_PLO + pb);
#pragma unroll
      for (int nt = 0; nt < 4; ++nt) {
        int vrow = nt * 16 + l15;  // d index
        int vb = SWZ((vrow << 7) + (koff << 1), vrow);
        bf16x8 vh = *(const bf16x8*)(smem + L_VHI + vb);
        bf16x8 vl = *(const bf16x8*)(smem + L_VLO + vb);
        oacc[nt] = MFMA16(ph, vh, oacc[nt]);
        oacc[nt] = MFMA16(ph, vl, oacc[nt]);
        oacc[nt] = MFMA16(pl, vh, oacc[nt]);
      }
    }
    // write packed hi/lo attn-out to d_out at UN-SHUFFLED position
#pragma unroll
    for (int nt = 0; nt < 4; ++nt) {
#pragma unroll
      for (int r = 0; r < 4; ++r) {
        int row = wv * 16 + l4 * 4 + r;
        if (row < 49) {
          float o = oacc[nt][r];
          u16 hi, lo; splitf(o, hi, lo);
          size_t idx = ((size_t)b * 25088 + row * 512 + wi) * 512 + h * 64 + nt * 16 + l15;
          outp[idx] = ((u32)hi << 16) | (u32)lo;
        }
      }
    }
    __syncthreads();
  }
}

// ============ K3: in-place proj GEMM over d_out rows ============
// WG owns 64 full rows: A staged (packed u32 -> hi/lo LDS) before barrier,
// fp32 result written only in epilogue -> no cross-WG hazard.
#define K3_SMEM 131072  // Ahi[64][512] + Alo[64][512] bf16

__global__ void __launch_bounds__(512, 2)
proj_rows(const u16* __restrict__ ws, const float* __restrict__ proj_b,
          u32* __restrict__ inout) {
  extern __shared__ char smem[];
  const int tid = threadIdx.x;
  const size_t rowbase = (size_t)blockIdx.x * 64;
  const u16* Bhi = ws + WS_PHI;
  const u16* Blo = ws + WS_PLO;

  for (int i = tid; i < 64 * 128; i += 512) {
    int r = i >> 7, c4 = i & 127;
    uint4 pv = *((const uint4*)(inout + (rowbase + r) * 512) + c4);
    ushort4 hs = make_ushort4((u16)(pv.x >> 16), (u16)(pv.y >> 16),
                              (u16)(pv.z >> 16), (u16)(pv.w >> 16));
    ushort4 ls = make_ushort4((u16)(pv.x & 0xFFFFu), (u16)(pv.y & 0xFFFFu),
                              (u16)(pv.z & 0xFFFFu), (u16)(pv.w & 0xFFFFu));
    int byte = SWZ((r << 10) + (c4 << 3), r);
    *(ushort4*)(smem + byte) = hs;
    *(ushort4*)(smem + 65536 + byte) = ls;
  }
  __syncthreads();

  const int lane = tid & 63, wv = tid >> 6;
  const int l15 = lane & 15, l4 = lane >> 4;

  f32x4 acc[4][4] = {};
  size_t nb[4];
#pragma unroll
  for (int nt = 0; nt < 4; ++nt) nb[nt] = (size_t)(wv * 64 + nt * 16 + l15) * 512;

#pragma unroll 2
  for (int ks = 0; ks < 16; ++ks) {
    int koff = ks * 32 + l4 * 8;
    bf16x8 ah[4], al[4];
#pragma unroll
    for (int mt = 0; mt < 4; ++mt) {
      int row = mt * 16 + l15;
      int byte = SWZ((row << 10) + (koff << 1), row);
      ah[mt] = *(const bf16x8*)(smem + byte);
      al[mt] = *(const bf16x8*)(smem + 65536 + byte);
    }
    bf16x8 bh[4], bl[4];
#pragma unroll
    for (int nt = 0; nt < 4; ++nt) {
      bh[nt] = *(const bf16x8*)(Bhi + nb[nt] + koff);
      bl[nt] = *(const bf16x8*)(Blo + nb[nt] + koff);
    }
#pragma unroll
    for (int mt = 0; mt < 4; ++mt) {
#pragma unroll
      for (int nt = 0; nt < 4; ++nt) {
        acc[mt][nt] = MFMA16(ah[mt], bh[nt], acc[mt][nt]);
        acc[mt][nt] = MFMA16(ah[mt], bl[nt], acc[mt][nt]);
        acc[mt][nt] = MFMA16(al[mt], bh[nt], acc[mt][nt]);
      }
    }
  }

  float* outf = (float*)inout;
#pragma unroll
  for (int mt = 0; mt < 4; ++mt) {
#pragma unroll
    for (int nt = 0; nt < 4; ++nt) {
      int n = wv * 64 + nt * 16 + l15;
      float bias = proj_b[n];
#pragma unroll
      for (int r = 0; r < 4; ++r) {
        int m = mt * 16 + l4 * 4 + r;
        outf[(rowbase + m) * 512 + n] = acc[mt][nt][r] + bias;
      }
    }
  }
}

// ============ launcher ============
extern "C" void kernel_launch(void* const* d_in, const int* in_sizes, int n_in,
                              void* d_out, int out_size, void* d_ws, size_t ws_size,
                              hipStream_t stream) {
  const float* x      = (const float*)d_in[0];
  // d_in[1] = coords (unused by the reference computation)
  const float* qkv_w  = (const float*)d_in[2];
  const float* qkv_b  = (const float*)d_in[3];
  const float* proj_w = (const float*)d_in[4];
  const float* proj_b = (const float*)d_in[5];
  u16* ws  = (u16*)d_ws;
  u32* out = (u32*)d_out;

  hipFuncSetAttribute((const void*)attn_win,
                      hipFuncAttributeMaxDynamicSharedMemorySize, K2_SMEM);
  hipFuncSetAttribute((const void*)proj_rows,
                      hipFuncAttributeMaxDynamicSharedMemorySize, K3_SMEM);

  prep_weights<<<1024, 256, 0, stream>>>(qkv_w, proj_w, ws);
  attn_win<<<4096, 256, K2_SMEM, stream>>>(x, qkv_b, ws, out);
  proj_rows<<<3136, 512, K3_SMEM, stream>>>(ws, proj_b, out);
}